// Round 6
// baseline (157.165 us; speedup 1.0000x reference)
//
#include <hip/hip_runtime.h>
#include <hip/hip_bf16.h>
#include <math.h>

#define BATCH 16
#define SEQ 4096
#define HDIM 64

typedef __attribute__((ext_vector_type(8))) short bf16x8;   // 8 bf16 = 4 VGPR
typedef __attribute__((ext_vector_type(4))) float f32x4;
typedef __attribute__((ext_vector_type(8))) unsigned short us8;

// softmax scale (1/8) * log2(e) folded into Wq -> softmax in exp2 space.
// No running max: |s| < ~25 worst case => exp2/f32 sums can't overflow.
#define QSCALE 0.1803368801111601f

static __device__ __forceinline__ float exp2_fast(float x) {
#if __has_builtin(__builtin_amdgcn_exp2f)
    return __builtin_amdgcn_exp2f(x);
#else
    float r; asm("v_exp_f32 %0, %1" : "=v"(r) : "v"(x)); return r;
#endif
}

// async global->LDS, 16B/lane. LDS dest = wave-uniform base + lane*16 (m104).
static __device__ __forceinline__ void load_lds16(const void* g, void* l) {
    __builtin_amdgcn_global_load_lds(
        (const __attribute__((address_space(1))) unsigned int*)g,
        (__attribute__((address_space(3))) unsigned int*)l,
        16, 0, 0);
}

static __device__ __forceinline__ unsigned short bf16bits(float f) {
    __hip_bfloat16 h = __float2bfloat16(f);
    return *(unsigned short*)&h;
}

// ---------------- W prep ----------------
// Wt[mat][n][k] bf16 LINEAR, k-contiguous (direct B-frag loads, no staging).
// QSCALE folded into Wq. 24 blocks x 64 thr; thread -> one 16B chunk.
__global__ __launch_bounds__(64)
void wprep_kernel(const float* __restrict__ Wq, const float* __restrict__ Wk,
                  const float* __restrict__ Wv, __hip_bfloat16* __restrict__ wt) {
    const int mat = blockIdx.x >> 3;
    const int part = blockIdx.x & 7;
    const int t = threadIdx.x;
    const int n = part * 8 + (t >> 3);
    const int s = t & 7;                      // k-chunk: k = s*8..s*8+7
    const float* W = (mat == 0) ? Wq : (mat == 1) ? Wk : Wv;
    const float sc = (mat == 0) ? QSCALE : 1.0f;
    us8 u;
    #pragma unroll
    for (int j = 0; j < 8; ++j)
        u[j] = bf16bits(W[(s * 8 + j) * HDIM + n] * sc);
    *(us8*)(wt + (size_t)(mat * 64 + n) * 64 + s * 8) = u;
}

// ---------------- QKV projection as MFMA GEMM ----------------
// 1024 blocks x 256 thr (4 waves, 16 rows each). LDS = ONE 16KB buffer:
// first the fp32 x tile (global_load_lds, XOR chunk swizzle), then reused as
// bf16 out-staging so every global store is a coalesced us8 row store.
// W B-frags loaded per-mat directly from global (24KB, L2-hot) -- no swt
// staging, low live-VGPR. Round-5 version held 49KB LDS (3 blocks/CU) and
// ~180 live VGPRs; this is the occupancy/latency-hiding fix.
__global__ __launch_bounds__(256)
void qkv_mfma_kernel(const float* __restrict__ x,
                     const __hip_bfloat16* __restrict__ wt,
                     __hip_bfloat16* __restrict__ qb,
                     __hip_bfloat16* __restrict__ kb,
                     __hip_bfloat16* __restrict__ vt) {
    __shared__ __attribute__((aligned(16))) float sx[64 * 64];   // 16 KB
    __hip_bfloat16 (*sout)[80] = (__hip_bfloat16 (*)[80])sx;     // reuse: 64x80 bf16 = 10.2 KB
    const int tid = threadIdx.x;
    const int wv = tid >> 6;
    const int lane = tid & 63;
    const int quad = lane >> 4;
    const int ml = lane & 15;
    const size_t row0 = (size_t)blockIdx.x * 64;
    const int batch = (int)(row0 >> 12);
    const int t0 = (int)(row0 & 4095);

    // stage x tile: slot (r, s) <- global chunk (r, c = s^(r&7))
    #pragma unroll
    for (int i = 0; i < 4; ++i) {
        const int slotbase = (wv * 4 + i) * 64;
        const int slot = slotbase + lane;
        const int r = slot >> 4, s = slot & 15;
        const int c = s ^ (r & 7);
        load_lds16(x + (row0 + r) * HDIM + c * 4, (char*)sx + (size_t)slotbase * 16);
    }
    asm volatile("s_waitcnt vmcnt(0)" ::: "memory");
    __syncthreads();

    // A-frags (rows wv*16+ml): chunks 2q,2q+1 (k<32) and 8+2q,9+2q (k>=32)
    const int rr = wv * 16 + ml;
    const int m7 = ml & 7;
    const float4* sx4 = (const float4*)sx;
    bf16x8 a0, a1;
    {
        float4 lo = sx4[rr * 16 + ((2 * quad) ^ m7)];
        float4 hi = sx4[rr * 16 + ((2 * quad + 1) ^ m7)];
        float t8[8] = {lo.x, lo.y, lo.z, lo.w, hi.x, hi.y, hi.z, hi.w};
        #pragma unroll
        for (int j = 0; j < 8; ++j) a0[j] = (short)bf16bits(t8[j]);
        lo = sx4[rr * 16 + ((8 + 2 * quad) ^ m7)];
        hi = sx4[rr * 16 + ((9 + 2 * quad) ^ m7)];
        float u8[8] = {lo.x, lo.y, lo.z, lo.w, hi.x, hi.y, hi.z, hi.w};
        #pragma unroll
        for (int j = 0; j < 8; ++j) a1[j] = (short)bf16bits(u8[j]);
    }
    __syncthreads();   // all A-frag reads done; sx buffer free for reuse

    #pragma unroll
    for (int mat = 0; mat < 3; ++mat) {
        // B-frags direct from global (L2-hot 24KB table)
        const __hip_bfloat16* wb = wt + (size_t)mat * 64 * 64;
        f32x4 acc[4];
        #pragma unroll
        for (int nt = 0; nt < 4; ++nt) {
            const int n = nt * 16 + ml;
            const bf16x8 bl = *(const bf16x8*)(wb + (size_t)n * 64 + quad * 8);
            const bf16x8 bh = *(const bf16x8*)(wb + (size_t)n * 64 + 32 + quad * 8);
            acc[nt] = __builtin_amdgcn_mfma_f32_16x16x32_bf16(a0, bl, (f32x4){0.f,0.f,0.f,0.f}, 0, 0, 0);
            acc[nt] = __builtin_amdgcn_mfma_f32_16x16x32_bf16(a1, bh, acc[nt], 0, 0, 0);
        }

        // C-frag -> LDS staging (Q/K row-major; V transposed) then coalesced store
        if (mat < 2) {
            #pragma unroll
            for (int nt = 0; nt < 4; ++nt)
                #pragma unroll
                for (int r = 0; r < 4; ++r)
                    sout[wv * 16 + quad * 4 + r][nt * 16 + ml] = __float2bfloat16(acc[nt][r]);
        } else {
            #pragma unroll
            for (int nt = 0; nt < 4; ++nt)
                #pragma unroll
                for (int r = 0; r < 4; ++r)
                    sout[nt * 16 + ml][wv * 16 + quad * 4 + r] = __float2bfloat16(acc[nt][r]);
        }
        __syncthreads();
        __hip_bfloat16* dst = (mat == 0) ? qb : (mat == 1) ? kb : vt;
        #pragma unroll
        for (int c2 = 0; c2 < 2; ++c2) {
            const int cc = c2 * 256 + tid;
            const int row = cc >> 3, g = cc & 7;
            us8 u = *(const us8*)&sout[row][g * 8];
            if (mat < 2)
                *(us8*)(dst + (row0 + row) * HDIM + g * 8) = u;
            else
                *(us8*)(dst + ((size_t)batch * HDIM + row) * SEQ + t0 + g * 8) = u;
        }
        __syncthreads();   // sout free before next mat overwrites
    }
}

// ---------------- MFMA flash attention (unchanged from round 4/5) ----------------
__global__ __launch_bounds__(256)
void flash_mfma_kernel(const __hip_bfloat16* __restrict__ qb,
                       const __hip_bfloat16* __restrict__ kbuf,
                       const __hip_bfloat16* __restrict__ vt,
                       float* __restrict__ out) {
    __shared__ __attribute__((aligned(16))) __hip_bfloat16 sk[64 * 64];
    __shared__ __attribute__((aligned(16))) __hip_bfloat16 sv[64 * 64];
    __shared__ __attribute__((aligned(16))) __hip_bfloat16 pb[4][16][72];
    const int tid = threadIdx.x;
    const int wv = tid >> 6;
    const int lane = tid & 63;
    const int quad = lane >> 4;
    const int ml = lane & 15;

    const int id = blockIdx.x;
    const int b = (((id >> 3) & 1) << 3) | (id & 7);  // id%8 pins XCD
    const int qt = 63 - (id >> 4);                    // heavy blocks first
    const int qbase = qt * 64 + wv * 16;
    const size_t bb = (size_t)b * SEQ * HDIM;

    const __hip_bfloat16* Q = qb + bb;
    const __hip_bfloat16* K = kbuf + bb;
    const __hip_bfloat16* VT = vt + bb;   // [b][64][SEQ]

    const bf16x8 a0 = *(const bf16x8*)(Q + (size_t)(qbase + ml) * HDIM + quad * 8);
    const bf16x8 a1 = *(const bf16x8*)(Q + (size_t)(qbase + ml) * HDIM + 32 + quad * 8);

    bf16x8 ones;
    #pragma unroll
    for (int j = 0; j < 8; ++j) ones[j] = (short)0x3F80;

    f32x4 acc[4];
    #pragma unroll
    for (int nt = 0; nt < 4; ++nt) acc[nt] = (f32x4){0.f, 0.f, 0.f, 0.f};
    f32x4 lacc = (f32x4){0.f, 0.f, 0.f, 0.f};

    const int s0 = wv * 128 + lane;
    const int s1 = s0 + 64;
    const int r0row = s0 >> 3, r0ch = (s0 & 7) ^ (r0row & 7);
    const int r1row = s1 >> 3, r1ch = (s1 & 7) ^ (r1row & 7);
    __hip_bfloat16* ldsb0k = sk + (size_t)(wv * 128) * 8;
    __hip_bfloat16* ldsb1k = sk + (size_t)(wv * 128 + 64) * 8;
    __hip_bfloat16* ldsb0v = sv + (size_t)(wv * 128) * 8;
    __hip_bfloat16* ldsb1v = sv + (size_t)(wv * 128 + 64) * 8;

    const int ntiles = qt + 1;
    for (int tile = 0; tile < ntiles; ++tile) {
        const int kb0 = tile * 64;
        __syncthreads();
        load_lds16(K + (size_t)(kb0 + r0row) * HDIM + r0ch * 8, ldsb0k);
        load_lds16(K + (size_t)(kb0 + r1row) * HDIM + r1ch * 8, ldsb1k);
        load_lds16(VT + (size_t)r0row * SEQ + kb0 + r0ch * 8, ldsb0v);
        load_lds16(VT + (size_t)r1row * SEQ + kb0 + r1ch * 8, ldsb1v);
        asm volatile("s_waitcnt vmcnt(0)" ::: "memory");
        __syncthreads();

        f32x4 s[4];
        #pragma unroll
        for (int t = 0; t < 4; ++t) {
            const int row = t * 16 + ml;
            const int rb = row << 3, rx = row & 7;
            const bf16x8 kl = *(const bf16x8*)(sk + (size_t)((rb | (quad ^ rx)) * 8));
            const bf16x8 kh = *(const bf16x8*)(sk + (size_t)((rb | ((quad + 4) ^ rx)) * 8));
            s[t] = __builtin_amdgcn_mfma_f32_16x16x32_bf16(a0, kl, (f32x4){0.f,0.f,0.f,0.f}, 0, 0, 0);
            s[t] = __builtin_amdgcn_mfma_f32_16x16x32_bf16(a1, kh, s[t], 0, 0, 0);
        }

        const bool edge = (tile == qt);
        #pragma unroll
        for (int t = 0; t < 4; ++t) {
            const int key = kb0 + t * 16 + ml;
            #pragma unroll
            for (int r = 0; r < 4; ++r) {
                float pv = exp2_fast(s[t][r]);
                if (edge && (key > qbase + quad * 4 + r)) pv = 0.f;
                pb[wv][quad * 4 + r][t * 16 + ml] = __float2bfloat16(pv);
            }
        }
        asm volatile("s_waitcnt lgkmcnt(0)" ::: "memory");
        const bf16x8 ap0 = *(const bf16x8*)&pb[wv][ml][quad * 8];
        const bf16x8 ap1 = *(const bf16x8*)&pb[wv][ml][32 + quad * 8];

        lacc = __builtin_amdgcn_mfma_f32_16x16x32_bf16(ap0, ones, lacc, 0, 0, 0);
        lacc = __builtin_amdgcn_mfma_f32_16x16x32_bf16(ap1, ones, lacc, 0, 0, 0);
        #pragma unroll
        for (int nt = 0; nt < 4; ++nt) {
            const int row = nt * 16 + ml;
            const int rb = row << 3, rx = row & 7;
            const bf16x8 vl = *(const bf16x8*)(sv + (size_t)((rb | (quad ^ rx)) * 8));
            const bf16x8 vh = *(const bf16x8*)(sv + (size_t)((rb | ((quad + 4) ^ rx)) * 8));
            acc[nt] = __builtin_amdgcn_mfma_f32_16x16x32_bf16(ap0, vl, acc[nt], 0, 0, 0);
            acc[nt] = __builtin_amdgcn_mfma_f32_16x16x32_bf16(ap1, vh, acc[nt], 0, 0, 0);
        }
    }

    #pragma unroll
    for (int r = 0; r < 4; ++r) {
        const float inv = 1.0f / lacc[r];
        const int row = qbase + quad * 4 + r;
        float* orow = out + bb + (size_t)row * HDIM + ml;
        orow[0]  = acc[0][r] * inv;
        orow[16] = acc[1][r] * inv;
        orow[32] = acc[2][r] * inv;
        orow[48] = acc[3][r] * inv;
    }
}

extern "C" void kernel_launch(void* const* d_in, const int* in_sizes, int n_in,
                              void* d_out, int out_size, void* d_ws, size_t ws_size,
                              hipStream_t stream) {
    const float* x  = (const float*)d_in[0];
    const float* Wq = (const float*)d_in[1];
    const float* Wk = (const float*)d_in[2];
    const float* Wv = (const float*)d_in[3];
    float* outp = (float*)d_out;

    const size_t elems = (size_t)BATCH * SEQ * HDIM;
    __hip_bfloat16* qb = (__hip_bfloat16*)d_ws;           // 8 MB
    __hip_bfloat16* kb = qb + elems;                      // 8 MB
    __hip_bfloat16* vt = kb + elems;                      // 8 MB, [b][d][t]
    __hip_bfloat16* wt = vt + elems;                      // 24 KB, linear Wt[mat][n][k]

    wprep_kernel<<<dim3(24), 64, 0, stream>>>(Wq, Wk, Wv, wt);
    qkv_mfma_kernel<<<dim3(BATCH * SEQ / 64), 256, 0, stream>>>(x, wt, qb, kb, vt);
    flash_mfma_kernel<<<dim3(BATCH * SEQ / 64), 256, 0, stream>>>(qb, kb, vt, outp);
}

// Round 7
// 157.016 us; speedup vs baseline: 1.0009x; 1.0009x over previous
//
#include <hip/hip_runtime.h>
#include <hip/hip_bf16.h>
#include <math.h>

#define BATCH 16
#define SEQ 4096
#define HDIM 64

typedef __attribute__((ext_vector_type(8))) short bf16x8;   // 8 bf16 = 4 VGPR
typedef __attribute__((ext_vector_type(4))) float f32x4;
typedef __attribute__((ext_vector_type(8))) unsigned short us8;

// softmax scale (1/8) * log2(e) folded into Wq -> softmax in exp2 space.
// No running max: |s| < ~25 worst case => exp2/f32 sums can't overflow.
#define QSCALE 0.1803368801111601f

static __device__ __forceinline__ float exp2_fast(float x) {
#if __has_builtin(__builtin_amdgcn_exp2f)
    return __builtin_amdgcn_exp2f(x);
#else
    float r; asm("v_exp_f32 %0, %1" : "=v"(r) : "v"(x)); return r;
#endif
}

// async global->LDS, 16B/lane. LDS dest = wave-uniform base + lane*16 (m104).
static __device__ __forceinline__ void load_lds16(const void* g, void* l) {
    __builtin_amdgcn_global_load_lds(
        (const __attribute__((address_space(1))) unsigned int*)g,
        (__attribute__((address_space(3))) unsigned int*)l,
        16, 0, 0);
}

static __device__ __forceinline__ unsigned short bf16bits(float f) {
    __hip_bfloat16 h = __float2bfloat16(f);
    return *(unsigned short*)&h;
}

// ---------------- W prep (unchanged from round 6) ----------------
__global__ __launch_bounds__(64)
void wprep_kernel(const float* __restrict__ Wq, const float* __restrict__ Wk,
                  const float* __restrict__ Wv, __hip_bfloat16* __restrict__ wt) {
    const int mat = blockIdx.x >> 3;
    const int part = blockIdx.x & 7;
    const int t = threadIdx.x;
    const int n = part * 8 + (t >> 3);
    const int s = t & 7;                      // k-chunk: k = s*8..s*8+7
    const float* W = (mat == 0) ? Wq : (mat == 1) ? Wk : Wv;
    const float sc = (mat == 0) ? QSCALE : 1.0f;
    us8 u;
    #pragma unroll
    for (int j = 0; j < 8; ++j)
        u[j] = bf16bits(W[(s * 8 + j) * HDIM + n] * sc);
    *(us8*)(wt + (size_t)(mat * 64 + n) * 64 + s * 8) = u;
}

// ---------------- QKV projection as MFMA GEMM (unchanged from round 6) ----------------
__global__ __launch_bounds__(256)
void qkv_mfma_kernel(const float* __restrict__ x,
                     const __hip_bfloat16* __restrict__ wt,
                     __hip_bfloat16* __restrict__ qb,
                     __hip_bfloat16* __restrict__ kb,
                     __hip_bfloat16* __restrict__ vt) {
    __shared__ __attribute__((aligned(16))) float sx[64 * 64];   // 16 KB
    __hip_bfloat16 (*sout)[80] = (__hip_bfloat16 (*)[80])sx;     // reuse for staging stores
    const int tid = threadIdx.x;
    const int wv = tid >> 6;
    const int lane = tid & 63;
    const int quad = lane >> 4;
    const int ml = lane & 15;
    const size_t row0 = (size_t)blockIdx.x * 64;
    const int batch = (int)(row0 >> 12);
    const int t0 = (int)(row0 & 4095);

    // stage x tile: slot (r, s) <- global chunk (r, c = s^(r&7))
    #pragma unroll
    for (int i = 0; i < 4; ++i) {
        const int slotbase = (wv * 4 + i) * 64;
        const int slot = slotbase + lane;
        const int r = slot >> 4, s = slot & 15;
        const int c = s ^ (r & 7);
        load_lds16(x + (row0 + r) * HDIM + c * 4, (char*)sx + (size_t)slotbase * 16);
    }
    asm volatile("s_waitcnt vmcnt(0)" ::: "memory");
    __syncthreads();

    // A-frags (rows wv*16+ml)
    const int rr = wv * 16 + ml;
    const int m7 = ml & 7;
    const float4* sx4 = (const float4*)sx;
    bf16x8 a0, a1;
    {
        float4 lo = sx4[rr * 16 + ((2 * quad) ^ m7)];
        float4 hi = sx4[rr * 16 + ((2 * quad + 1) ^ m7)];
        float t8[8] = {lo.x, lo.y, lo.z, lo.w, hi.x, hi.y, hi.z, hi.w};
        #pragma unroll
        for (int j = 0; j < 8; ++j) a0[j] = (short)bf16bits(t8[j]);
        lo = sx4[rr * 16 + ((8 + 2 * quad) ^ m7)];
        hi = sx4[rr * 16 + ((9 + 2 * quad) ^ m7)];
        float u8[8] = {lo.x, lo.y, lo.z, lo.w, hi.x, hi.y, hi.z, hi.w};
        #pragma unroll
        for (int j = 0; j < 8; ++j) a1[j] = (short)bf16bits(u8[j]);
    }
    __syncthreads();   // sx free for reuse

    #pragma unroll
    for (int mat = 0; mat < 3; ++mat) {
        const __hip_bfloat16* wb = wt + (size_t)mat * 64 * 64;
        f32x4 acc[4];
        #pragma unroll
        for (int nt = 0; nt < 4; ++nt) {
            const int n = nt * 16 + ml;
            const bf16x8 bl = *(const bf16x8*)(wb + (size_t)n * 64 + quad * 8);
            const bf16x8 bh = *(const bf16x8*)(wb + (size_t)n * 64 + 32 + quad * 8);
            acc[nt] = __builtin_amdgcn_mfma_f32_16x16x32_bf16(a0, bl, (f32x4){0.f,0.f,0.f,0.f}, 0, 0, 0);
            acc[nt] = __builtin_amdgcn_mfma_f32_16x16x32_bf16(a1, bh, acc[nt], 0, 0, 0);
        }

        if (mat < 2) {
            #pragma unroll
            for (int nt = 0; nt < 4; ++nt)
                #pragma unroll
                for (int r = 0; r < 4; ++r)
                    sout[wv * 16 + quad * 4 + r][nt * 16 + ml] = __float2bfloat16(acc[nt][r]);
        } else {
            #pragma unroll
            for (int nt = 0; nt < 4; ++nt)
                #pragma unroll
                for (int r = 0; r < 4; ++r)
                    sout[nt * 16 + ml][wv * 16 + quad * 4 + r] = __float2bfloat16(acc[nt][r]);
        }
        __syncthreads();
        __hip_bfloat16* dst = (mat == 0) ? qb : (mat == 1) ? kb : vt;
        #pragma unroll
        for (int c2 = 0; c2 < 2; ++c2) {
            const int cc = c2 * 256 + tid;
            const int row = cc >> 3, g = cc & 7;
            us8 u = *(const us8*)&sout[row][g * 8];
            if (mat < 2)
                *(us8*)(dst + (row0 + row) * HDIM + g * 8) = u;
            else
                *(us8*)(dst + ((size_t)batch * HDIM + row) * SEQ + t0 + g * 8) = u;
        }
        __syncthreads();
    }
}

// ---------------- MFMA flash attention, double-buffered staging ----------------
// Round 4-6 structure stalled every tile on s_waitcnt vmcnt(0) + 2 barriers
// with the K/V staging latency (200-900cy) fully exposed. Now: prefetch tile
// t+1 into the other LDS buffer at the top of iter t, compute tile t, THEN
// drain vmcnt + single barrier -> staging latency hides behind compute and
// barrier count halves.
__global__ __launch_bounds__(256)
void flash_mfma_kernel(const __hip_bfloat16* __restrict__ qb,
                       const __hip_bfloat16* __restrict__ kbuf,
                       const __hip_bfloat16* __restrict__ vt,
                       float* __restrict__ out) {
    __shared__ __attribute__((aligned(16))) __hip_bfloat16 sk[2][64 * 64];
    __shared__ __attribute__((aligned(16))) __hip_bfloat16 sv[2][64 * 64];
    __shared__ __attribute__((aligned(16))) __hip_bfloat16 pb[4][16][72];
    const int tid = threadIdx.x;
    const int wv = tid >> 6;
    const int lane = tid & 63;
    const int quad = lane >> 4;
    const int ml = lane & 15;

    const int id = blockIdx.x;
    const int b = (((id >> 3) & 1) << 3) | (id & 7);  // id%8 pins XCD
    const int qt = 63 - (id >> 4);                    // heavy blocks first
    const int qbase = qt * 64 + wv * 16;
    const size_t bb = (size_t)b * SEQ * HDIM;

    const __hip_bfloat16* Q = qb + bb;
    const __hip_bfloat16* K = kbuf + bb;
    const __hip_bfloat16* VT = vt + bb;   // [b][64][SEQ]

    const bf16x8 a0 = *(const bf16x8*)(Q + (size_t)(qbase + ml) * HDIM + quad * 8);
    const bf16x8 a1 = *(const bf16x8*)(Q + (size_t)(qbase + ml) * HDIM + 32 + quad * 8);

    bf16x8 ones;
    #pragma unroll
    for (int j = 0; j < 8; ++j) ones[j] = (short)0x3F80;

    f32x4 acc[4];
    #pragma unroll
    for (int nt = 0; nt < 4; ++nt) acc[nt] = (f32x4){0.f, 0.f, 0.f, 0.f};
    f32x4 lacc = (f32x4){0.f, 0.f, 0.f, 0.f};

    // staging geometry: 2 rounds x 64 lanes per wave, XOR chunk swizzle
    const int s0 = wv * 128 + lane;
    const int s1 = s0 + 64;
    const int r0row = s0 >> 3, r0ch = (s0 & 7) ^ (r0row & 7);
    const int r1row = s1 >> 3, r1ch = (s1 & 7) ^ (r1row & 7);
    const int d0 = (wv * 128) * 8;          // lds element offsets
    const int d1 = (wv * 128 + 64) * 8;

    const int ntiles = qt + 1;

    // prologue: stage tile 0 into buffer 0
    load_lds16(K + (size_t)r0row * HDIM + r0ch * 8, sk[0] + d0);
    load_lds16(K + (size_t)r1row * HDIM + r1ch * 8, sk[0] + d1);
    load_lds16(VT + (size_t)r0row * SEQ + r0ch * 8, sv[0] + d0);
    load_lds16(VT + (size_t)r1row * SEQ + r1ch * 8, sv[0] + d1);
    asm volatile("s_waitcnt vmcnt(0)" ::: "memory");
    __syncthreads();

    for (int tile = 0; tile < ntiles; ++tile) {
        const int kb0 = tile * 64;
        const int sel = tile & 1, nsel = sel ^ 1;
        const __hip_bfloat16* cs_k = sk[sel];
        const __hip_bfloat16* cs_v = sv[sel];

        // prefetch tile+1 into the other buffer (uniform branch)
        if (tile + 1 < ntiles) {
            const int nk = kb0 + 64;
            load_lds16(K + (size_t)(nk + r0row) * HDIM + r0ch * 8, sk[nsel] + d0);
            load_lds16(K + (size_t)(nk + r1row) * HDIM + r1ch * 8, sk[nsel] + d1);
            load_lds16(VT + (size_t)r0row * SEQ + nk + r0ch * 8, sv[nsel] + d0);
            load_lds16(VT + (size_t)r1row * SEQ + nk + r1ch * 8, sv[nsel] + d1);
        }

        // --- S = Q K^T ---
        f32x4 s[4];
        #pragma unroll
        for (int t = 0; t < 4; ++t) {
            const int row = t * 16 + ml;
            const int rb = row << 3, rx = row & 7;
            const bf16x8 kl = *(const bf16x8*)(cs_k + (size_t)((rb | (quad ^ rx)) * 8));
            const bf16x8 kh = *(const bf16x8*)(cs_k + (size_t)((rb | ((quad + 4) ^ rx)) * 8));
            s[t] = __builtin_amdgcn_mfma_f32_16x16x32_bf16(a0, kl, (f32x4){0.f,0.f,0.f,0.f}, 0, 0, 0);
            s[t] = __builtin_amdgcn_mfma_f32_16x16x32_bf16(a1, kh, s[t], 0, 0, 0);
        }

        // --- p = exp2(s), causal zero on the diagonal tile, scatter to pb ---
        const bool edge = (tile == qt);
        #pragma unroll
        for (int t = 0; t < 4; ++t) {
            const int key = kb0 + t * 16 + ml;
            #pragma unroll
            for (int r = 0; r < 4; ++r) {
                float pv = exp2_fast(s[t][r]);
                if (edge && (key > qbase + quad * 4 + r)) pv = 0.f;
                pb[wv][quad * 4 + r][t * 16 + ml] = __float2bfloat16(pv);
            }
        }
        asm volatile("s_waitcnt lgkmcnt(0)" ::: "memory");
        const bf16x8 ap0 = *(const bf16x8*)&pb[wv][ml][quad * 8];
        const bf16x8 ap1 = *(const bf16x8*)&pb[wv][ml][32 + quad * 8];

        // --- l row-sums (ones-B MFMA) + PV ---
        lacc = __builtin_amdgcn_mfma_f32_16x16x32_bf16(ap0, ones, lacc, 0, 0, 0);
        lacc = __builtin_amdgcn_mfma_f32_16x16x32_bf16(ap1, ones, lacc, 0, 0, 0);
        #pragma unroll
        for (int nt = 0; nt < 4; ++nt) {
            const int row = nt * 16 + ml;
            const int rb = row << 3, rx = row & 7;
            const bf16x8 vl = *(const bf16x8*)(cs_v + (size_t)((rb | (quad ^ rx)) * 8));
            const bf16x8 vh = *(const bf16x8*)(cs_v + (size_t)((rb | ((quad + 4) ^ rx)) * 8));
            acc[nt] = __builtin_amdgcn_mfma_f32_16x16x32_bf16(ap0, vl, acc[nt], 0, 0, 0);
            acc[nt] = __builtin_amdgcn_mfma_f32_16x16x32_bf16(ap1, vh, acc[nt], 0, 0, 0);
        }

        // drain own prefetch, then single barrier: next iter may overwrite
        // this tile's buffer and read the prefetched one
        asm volatile("s_waitcnt vmcnt(0)" ::: "memory");
        __syncthreads();
    }

    // epilogue: out[row][nt*16+ml] = acc/l (C-layout: row=quad*4+r, col=ml)
    #pragma unroll
    for (int r = 0; r < 4; ++r) {
        const float inv = 1.0f / lacc[r];
        const int row = qbase + quad * 4 + r;
        float* orow = out + bb + (size_t)row * HDIM + ml;
        orow[0]  = acc[0][r] * inv;
        orow[16] = acc[1][r] * inv;
        orow[32] = acc[2][r] * inv;
        orow[48] = acc[3][r] * inv;
    }
}

extern "C" void kernel_launch(void* const* d_in, const int* in_sizes, int n_in,
                              void* d_out, int out_size, void* d_ws, size_t ws_size,
                              hipStream_t stream) {
    const float* x  = (const float*)d_in[0];
    const float* Wq = (const float*)d_in[1];
    const float* Wk = (const float*)d_in[2];
    const float* Wv = (const float*)d_in[3];
    float* outp = (float*)d_out;

    const size_t elems = (size_t)BATCH * SEQ * HDIM;
    __hip_bfloat16* qb = (__hip_bfloat16*)d_ws;           // 8 MB
    __hip_bfloat16* kb = qb + elems;                      // 8 MB
    __hip_bfloat16* vt = kb + elems;                      // 8 MB, [b][d][t]
    __hip_bfloat16* wt = vt + elems;                      // 24 KB, linear Wt[mat][n][k]

    wprep_kernel<<<dim3(24), 64, 0, stream>>>(Wq, Wk, Wv, wt);
    qkv_mfma_kernel<<<dim3(BATCH * SEQ / 64), 256, 0, stream>>>(x, wt, qb, kb, vt);
    flash_mfma_kernel<<<dim3(BATCH * SEQ / 64), 256, 0, stream>>>(qb, kb, vt, outp);
}

// Round 8
// 149.155 us; speedup vs baseline: 1.0537x; 1.0527x over previous
//
#include <hip/hip_runtime.h>
#include <hip/hip_bf16.h>
#include <math.h>

#define BATCH 16
#define SEQ 4096
#define HDIM 64

typedef __attribute__((ext_vector_type(8))) short bf16x8;   // 8 bf16 = 4 VGPR
typedef __attribute__((ext_vector_type(4))) float f32x4;
typedef __attribute__((ext_vector_type(8))) unsigned short us8;

// softmax scale (1/8) * log2(e) folded into Wq -> softmax in exp2 space.
// No running max: |s| < ~25 worst case => exp2/f32 sums can't overflow.
#define QSCALE 0.1803368801111601f

static __device__ __forceinline__ float exp2_fast(float x) {
#if __has_builtin(__builtin_amdgcn_exp2f)
    return __builtin_amdgcn_exp2f(x);
#else
    float r; asm("v_exp_f32 %0, %1" : "=v"(r) : "v"(x)); return r;
#endif
}

// async global->LDS, 16B/lane. LDS dest = wave-uniform base + lane*16 (m104).
static __device__ __forceinline__ void load_lds16(const void* g, void* l) {
    __builtin_amdgcn_global_load_lds(
        (const __attribute__((address_space(1))) unsigned int*)g,
        (__attribute__((address_space(3))) unsigned int*)l,
        16, 0, 0);
}

static __device__ __forceinline__ unsigned short bf16bits(float f) {
    __hip_bfloat16 h = __float2bfloat16(f);
    return *(unsigned short*)&h;
}

// ---------------- QKV projection (wprep folded in) ----------------
// 1024 blocks x 256 thr. Per block: async-stage x tile (16KB, XOR-swizzled)
// while converting W fp32->bf16 into a 24KB XOR-swizzled LDS table
// (coalesced global reads; W is L2-hot after the first blocks). B-frags then
// come from LDS (2-way reads = free). Removes the separate wprep dispatch,
// its dependency gap, and all wt global traffic.
__global__ __launch_bounds__(256)
void qkv_mfma_kernel(const float* __restrict__ x,
                     const float* __restrict__ Wq,
                     const float* __restrict__ Wk,
                     const float* __restrict__ Wv,
                     __hip_bfloat16* __restrict__ qb,
                     __hip_bfloat16* __restrict__ kb,
                     __hip_bfloat16* __restrict__ vt) {
    __shared__ __attribute__((aligned(16))) float sx[64 * 64];                 // 16 KB
    __shared__ __attribute__((aligned(16))) __hip_bfloat16 swt[3 * 64 * 64];   // 24 KB
    __hip_bfloat16 (*sout)[80] = (__hip_bfloat16 (*)[80])sx;                   // overlay
    const int tid = threadIdx.x;
    const int wv = tid >> 6;
    const int lane = tid & 63;
    const int quad = lane >> 4;
    const int ml = lane & 15;
    const size_t row0 = (size_t)blockIdx.x * 64;
    const int batch = (int)(row0 >> 12);
    const int t0 = (int)(row0 & 4095);

    // 1) async x staging: slot (r, s) <- global chunk (r, c = s^(r&7))
    #pragma unroll
    for (int i = 0; i < 4; ++i) {
        const int slotbase = (wv * 4 + i) * 64;
        const int slot = slotbase + lane;
        const int r = slot >> 4, s = slot & 15;
        const int c = s ^ (r & 7);
        load_lds16(x + (row0 + r) * HDIM + c * 4, (char*)sx + (size_t)slotbase * 16);
    }

    // 2) W -> swt (swizzled [mat][n][k]) under the staging latency.
    // flat f = k*64+n; thread t covers f = t, t+256, ... (n = t&63 fixed).
    #pragma unroll
    for (int mat = 0; mat < 3; ++mat) {
        const float* W = (mat == 0) ? Wq : (mat == 1) ? Wk : Wv;
        const float sc = (mat == 0) ? QSCALE : 1.0f;
        const int n = tid & 63;
        #pragma unroll
        for (int i = 0; i < 16; ++i) {
            const int f = i * 256 + tid;
            const int k = f >> 6;
            swt[mat * 4096 + n * 64 + (((k >> 3) ^ (n & 7)) << 3) + (k & 7)] =
                __float2bfloat16(W[f] * sc);
        }
    }
    asm volatile("s_waitcnt vmcnt(0)" ::: "memory");
    __syncthreads();

    // 3) A-frags (rows wv*16+ml)
    const int rr = wv * 16 + ml;
    const int m7 = ml & 7;
    const float4* sx4 = (const float4*)sx;
    bf16x8 a0, a1;
    {
        float4 lo = sx4[rr * 16 + ((2 * quad) ^ m7)];
        float4 hi = sx4[rr * 16 + ((2 * quad + 1) ^ m7)];
        float t8[8] = {lo.x, lo.y, lo.z, lo.w, hi.x, hi.y, hi.z, hi.w};
        #pragma unroll
        for (int j = 0; j < 8; ++j) a0[j] = (short)bf16bits(t8[j]);
        lo = sx4[rr * 16 + ((8 + 2 * quad) ^ m7)];
        hi = sx4[rr * 16 + ((9 + 2 * quad) ^ m7)];
        float u8[8] = {lo.x, lo.y, lo.z, lo.w, hi.x, hi.y, hi.z, hi.w};
        #pragma unroll
        for (int j = 0; j < 8; ++j) a1[j] = (short)bf16bits(u8[j]);
    }
    __syncthreads();   // sx free for reuse as sout

    #pragma unroll
    for (int mat = 0; mat < 3; ++mat) {
        const __hip_bfloat16* wb = swt + mat * 4096;
        f32x4 acc[4];
        #pragma unroll
        for (int nt = 0; nt < 4; ++nt) {
            const int n = nt * 16 + ml;
            const int nx = n & 7;
            const bf16x8 bl = *(const bf16x8*)(wb + (size_t)n * 64 + (size_t)((quad) ^ nx) * 8);
            const bf16x8 bh = *(const bf16x8*)(wb + (size_t)n * 64 + (size_t)((quad + 4) ^ nx) * 8);
            acc[nt] = __builtin_amdgcn_mfma_f32_16x16x32_bf16(a0, bl, (f32x4){0.f,0.f,0.f,0.f}, 0, 0, 0);
            acc[nt] = __builtin_amdgcn_mfma_f32_16x16x32_bf16(a1, bh, acc[nt], 0, 0, 0);
        }

        if (mat < 2) {
            #pragma unroll
            for (int nt = 0; nt < 4; ++nt)
                #pragma unroll
                for (int r = 0; r < 4; ++r)
                    sout[wv * 16 + quad * 4 + r][nt * 16 + ml] = __float2bfloat16(acc[nt][r]);
        } else {
            #pragma unroll
            for (int nt = 0; nt < 4; ++nt)
                #pragma unroll
                for (int r = 0; r < 4; ++r)
                    sout[nt * 16 + ml][wv * 16 + quad * 4 + r] = __float2bfloat16(acc[nt][r]);
        }
        __syncthreads();
        __hip_bfloat16* dst = (mat == 0) ? qb : (mat == 1) ? kb : vt;
        #pragma unroll
        for (int c2 = 0; c2 < 2; ++c2) {
            const int cc = c2 * 256 + tid;
            const int row = cc >> 3, g = cc & 7;
            us8 u = *(const us8*)&sout[row][g * 8];
            if (mat < 2)
                *(us8*)(dst + (row0 + row) * HDIM + g * 8) = u;
            else
                *(us8*)(dst + ((size_t)batch * HDIM + row) * SEQ + t0 + g * 8) = u;
        }
        __syncthreads();
    }
}

// ---------------- MFMA flash attention, balanced grid ----------------
// Single-buffer staging (dbuf measured neutral: m99/m100 pattern confirmed
// in round 7) -> 25.6KB LDS -> 4 blocks/CU, all 1024 blocks resident at t=0.
// qt map: residency classes id%256 get qt {63-mid, 32+mid, 31-mid, mid}
// -> every CU's 4 blocks sum to exactly 130 tile-steps (was 100..160, a
// 1.23x static straggler factor).
__global__ __launch_bounds__(256)
void flash_mfma_kernel(const __hip_bfloat16* __restrict__ qb,
                       const __hip_bfloat16* __restrict__ kbuf,
                       const __hip_bfloat16* __restrict__ vt,
                       float* __restrict__ out) {
    __shared__ __attribute__((aligned(16))) __hip_bfloat16 sk[64 * 64];
    __shared__ __attribute__((aligned(16))) __hip_bfloat16 sv[64 * 64];
    __shared__ __attribute__((aligned(16))) __hip_bfloat16 pb[4][16][72];
    const int tid = threadIdx.x;
    const int wv = tid >> 6;
    const int lane = tid & 63;
    const int quad = lane >> 4;
    const int ml = lane & 15;

    const int id = blockIdx.x;
    const int b = id & 15;                 // id%8 = b%8 pins batch->XCD (2 batches/XCD)
    const int t = id >> 4;                 // [0,64)
    const int hi = t >> 4, mid = t & 15;
    const int qt = (hi == 0) ? (63 - mid)
                 : (hi == 1) ? (32 + mid)
                 : (hi == 2) ? (31 - mid) : mid;
    const int qbase = qt * 64 + wv * 16;
    const size_t bb = (size_t)b * SEQ * HDIM;

    const __hip_bfloat16* Q = qb + bb;
    const __hip_bfloat16* K = kbuf + bb;
    const __hip_bfloat16* VT = vt + bb;   // [b][64][SEQ]

    const bf16x8 a0 = *(const bf16x8*)(Q + (size_t)(qbase + ml) * HDIM + quad * 8);
    const bf16x8 a1 = *(const bf16x8*)(Q + (size_t)(qbase + ml) * HDIM + 32 + quad * 8);

    bf16x8 ones;
    #pragma unroll
    for (int j = 0; j < 8; ++j) ones[j] = (short)0x3F80;

    f32x4 acc[4];
    #pragma unroll
    for (int nt = 0; nt < 4; ++nt) acc[nt] = (f32x4){0.f, 0.f, 0.f, 0.f};
    f32x4 lacc = (f32x4){0.f, 0.f, 0.f, 0.f};

    // staging geometry: 2 rounds x 64 lanes per wave, XOR chunk swizzle
    const int s0 = wv * 128 + lane;
    const int s1 = s0 + 64;
    const int r0row = s0 >> 3, r0ch = (s0 & 7) ^ (r0row & 7);
    const int r1row = s1 >> 3, r1ch = (s1 & 7) ^ (r1row & 7);
    __hip_bfloat16* ldsb0k = sk + (size_t)(wv * 128) * 8;
    __hip_bfloat16* ldsb1k = sk + (size_t)(wv * 128 + 64) * 8;
    __hip_bfloat16* ldsb0v = sv + (size_t)(wv * 128) * 8;
    __hip_bfloat16* ldsb1v = sv + (size_t)(wv * 128 + 64) * 8;

    const int ntiles = qt + 1;
    for (int tile = 0; tile < ntiles; ++tile) {
        const int kb0 = tile * 64;
        __syncthreads();
        load_lds16(K + (size_t)(kb0 + r0row) * HDIM + r0ch * 8, ldsb0k);
        load_lds16(K + (size_t)(kb0 + r1row) * HDIM + r1ch * 8, ldsb1k);
        load_lds16(VT + (size_t)r0row * SEQ + kb0 + r0ch * 8, ldsb0v);
        load_lds16(VT + (size_t)r1row * SEQ + kb0 + r1ch * 8, ldsb1v);
        asm volatile("s_waitcnt vmcnt(0)" ::: "memory");
        __syncthreads();

        f32x4 s[4];
        #pragma unroll
        for (int tt = 0; tt < 4; ++tt) {
            const int row = tt * 16 + ml;
            const int rb = row << 3, rx = row & 7;
            const bf16x8 kl = *(const bf16x8*)(sk + (size_t)((rb | (quad ^ rx)) * 8));
            const bf16x8 kh = *(const bf16x8*)(sk + (size_t)((rb | ((quad + 4) ^ rx)) * 8));
            s[tt] = __builtin_amdgcn_mfma_f32_16x16x32_bf16(a0, kl, (f32x4){0.f,0.f,0.f,0.f}, 0, 0, 0);
            s[tt] = __builtin_amdgcn_mfma_f32_16x16x32_bf16(a1, kh, s[tt], 0, 0, 0);
        }

        const bool edge = (tile == qt);
        #pragma unroll
        for (int tt = 0; tt < 4; ++tt) {
            const int key = kb0 + tt * 16 + ml;
            #pragma unroll
            for (int r = 0; r < 4; ++r) {
                float pv = exp2_fast(s[tt][r]);
                if (edge && (key > qbase + quad * 4 + r)) pv = 0.f;
                pb[wv][quad * 4 + r][tt * 16 + ml] = __float2bfloat16(pv);
            }
        }
        asm volatile("s_waitcnt lgkmcnt(0)" ::: "memory");
        const bf16x8 ap0 = *(const bf16x8*)&pb[wv][ml][quad * 8];
        const bf16x8 ap1 = *(const bf16x8*)&pb[wv][ml][32 + quad * 8];

        lacc = __builtin_amdgcn_mfma_f32_16x16x32_bf16(ap0, ones, lacc, 0, 0, 0);
        lacc = __builtin_amdgcn_mfma_f32_16x16x32_bf16(ap1, ones, lacc, 0, 0, 0);
        #pragma unroll
        for (int nt = 0; nt < 4; ++nt) {
            const int row = nt * 16 + ml;
            const int rb = row << 3, rx = row & 7;
            const bf16x8 vl = *(const bf16x8*)(sv + (size_t)((rb | (quad ^ rx)) * 8));
            const bf16x8 vh = *(const bf16x8*)(sv + (size_t)((rb | ((quad + 4) ^ rx)) * 8));
            acc[nt] = __builtin_amdgcn_mfma_f32_16x16x32_bf16(ap0, vl, acc[nt], 0, 0, 0);
            acc[nt] = __builtin_amdgcn_mfma_f32_16x16x32_bf16(ap1, vh, acc[nt], 0, 0, 0);
        }
    }

    // epilogue: out[row][nt*16+ml] = acc/l (C-layout: row=quad*4+r, col=ml)
    #pragma unroll
    for (int r = 0; r < 4; ++r) {
        const float inv = 1.0f / lacc[r];
        const int row = qbase + quad * 4 + r;
        float* orow = out + bb + (size_t)row * HDIM + ml;
        orow[0]  = acc[0][r] * inv;
        orow[16] = acc[1][r] * inv;
        orow[32] = acc[2][r] * inv;
        orow[48] = acc[3][r] * inv;
    }
}

extern "C" void kernel_launch(void* const* d_in, const int* in_sizes, int n_in,
                              void* d_out, int out_size, void* d_ws, size_t ws_size,
                              hipStream_t stream) {
    const float* x  = (const float*)d_in[0];
    const float* Wq = (const float*)d_in[1];
    const float* Wk = (const float*)d_in[2];
    const float* Wv = (const float*)d_in[3];
    float* outp = (float*)d_out;

    const size_t elems = (size_t)BATCH * SEQ * HDIM;
    __hip_bfloat16* qb = (__hip_bfloat16*)d_ws;           // 8 MB
    __hip_bfloat16* kb = qb + elems;                      // 8 MB
    __hip_bfloat16* vt = kb + elems;                      // 8 MB, [b][d][t]

    qkv_mfma_kernel<<<dim3(BATCH * SEQ / 64), 256, 0, stream>>>(x, Wq, Wk, Wv, qb, kb, vt);
    flash_mfma_kernel<<<dim3(BATCH * SEQ / 64), 256, 0, stream>>>(qb, kb, vt, outp);
}